// Round 10
// baseline (674.364 us; speedup 1.0000x reference)
//
#include <hip/hip_runtime.h>
#include <hip/hip_cooperative_groups.h>
namespace cg = cooperative_groups;

#define NN 50000
#define NE 800000
#define DF 128
#define NG 64
#define NC 10
#define NBK 98            // ceil(NN/512) coarse buckets (dst>>9)
#define PART_CHUNK 4096
#define PART_GRID 196     // 196*4096 >= 800000
#define ACAP 12288        // arena capacity per bucket (avg 8163, max ~8600)
#define FINE_CAP 12288
#define RT 136            // h staging row stride (ushorts)
#define CAST_GRID 6250    // NN*DF/4/256
#define GEMM_TILES 782    // ceil(NN/64)

typedef short bf16x8 __attribute__((ext_vector_type(8)));
typedef float f32x4  __attribute__((ext_vector_type(4)));

__device__ __forceinline__ void atomAddF(float* p, float v) {
  __hip_atomic_fetch_add(p, v, __ATOMIC_RELAXED, __HIP_MEMORY_SCOPE_AGENT);
}
__device__ __forceinline__ float b2f(unsigned short u) {
  union { unsigned int i; float f; } v; v.i = (unsigned int)u << 16; return v.f;
}
__device__ __forceinline__ unsigned int f2b(float f) {
  unsigned int i = __float_as_uint(f);
  return (i + 0x7fffu + ((i >> 16) & 1u)) >> 16;
}

struct KArgs {
  const float* x; const int* src; const int* dst; const int* batch;
  const float *W1a, *b1a, *W1b, *b1b, *W2a, *b2a, *W2b, *b2b, *Wfc, *bfc;
  float* out;
  unsigned short *xb, *A, *H, *Wt;
  float* sums; int* cnts; int* cnt_b; int* rs;
  unsigned short* es; unsigned int* arena;
};

struct SmU {
  union {
    struct { unsigned int stage[PART_CHUNK]; int lhist[128]; int lcnt[128]; int lcur[128]; int gbase[128]; } part;
    struct { unsigned short les[FINE_CAP]; int bins[4096]; int partials[256]; int basebuf[128]; } fine;
    struct { unsigned short WaL[2048 * 8]; unsigned short hL[4][16 * RT]; } gemm;
  };
};

// ---- phase: cast x->bf16 and weights->fragment-major bf16 ----
__device__ __forceinline__ void d_prep(int vb, const KArgs& a, int tid) {
  if (vb < CAST_GRID) {
    const int i = vb * 256 + tid;
    const float4 v = reinterpret_cast<const float4*>(a.x)[i];
    uint2 o;
    o.x = f2b(v.x) | (f2b(v.y) << 16);
    o.y = f2b(v.z) | (f2b(v.w) << 16);
    reinterpret_cast<uint2*>(a.xb)[i] = o;
  } else {
    const int o = (vb - CAST_GRID) * 256 + tid;
    const int mat = o >> 11;
    const float* W = (mat == 0) ? a.W1a : (mat == 1) ? a.W1b : (mat == 2) ? a.W2a : a.W2b;
    const int rem = o & 2047;
    const int kb = rem >> 7, n = rem & 127;
    unsigned int u[8];
#pragma unroll
    for (int j = 0; j < 8; ++j) u[j] = f2b(W[(size_t)(kb * 8 + j) * DF + n]);
    uint4 p;
    p.x = u[0] | (u[1] << 16);
    p.y = u[2] | (u[3] << 16);
    p.z = u[4] | (u[5] << 16);
    p.w = u[6] | (u[7] << 16);
    *reinterpret_cast<uint4*>(a.Wt + (size_t)mat * DF * DF + (size_t)rem * 8) = p;
  }
}

// ---- phase: partition edges into bucket arenas ----
__device__ void d_part(int vb, const KArgs& a, SmU& sm, int tid) {
  const int e0 = vb * PART_CHUNK;
  const int nE = min(PART_CHUNK, NE - e0);
  for (int i = tid; i < 128; i += 256) sm.part.lhist[i] = 0;
  __syncthreads();
  unsigned int pk[16]; int bk[16];
#pragma unroll
  for (int i = 0; i < 16; ++i) {
    const int e = e0 + i * 256 + tid;
    if (e < NE) {
      const int d = a.dst[e], s = a.src[e];
      const int b = d >> 9;
      bk[i] = b;
      pk[i] = ((unsigned int)b << 25) | ((unsigned int)(d & 511) << 16) | (unsigned int)s;
      atomicAdd(&sm.part.lhist[b], 1);
    } else bk[i] = -1;
  }
  __syncthreads();
  for (int i = tid; i < 128; i += 256) sm.part.lcnt[i] = sm.part.lhist[i];
  __syncthreads();
  for (int off = 1; off < 128; off <<= 1) {
    int v = 0;
    if (tid < 128 && tid >= off) v = sm.part.lhist[tid - off];
    __syncthreads();
    if (tid < 128) sm.part.lhist[tid] += v;
    __syncthreads();
  }
  if (tid < 128) sm.part.lcur[tid] = sm.part.lhist[tid] - sm.part.lcnt[tid];
  __syncthreads();
#pragma unroll
  for (int i = 0; i < 16; ++i)
    if (bk[i] >= 0) {
      const int pos = atomicAdd(&sm.part.lcur[bk[i]], 1);
      sm.part.stage[pos] = pk[i];
    }
  __syncthreads();
  if (tid < NBK) {
    const int c = sm.part.lcnt[tid];
    if (c > 0) sm.part.gbase[tid] = atomicAdd(&a.cnt_b[tid], c);
  }
  __syncthreads();
  for (int idx = tid; idx < nE; idx += 256) {
    const unsigned int p = sm.part.stage[idx];
    const int b = (int)(p >> 25);
    const int loff = sm.part.lhist[b] - sm.part.lcnt[b];
    a.arena[(size_t)b * ACAP + sm.part.gbase[b] + (idx - loff)] = p;
  }
}

// ---- phase: per-bucket counting sort by (dstlocal, src>>13); self-computed base ----
__device__ void d_fine(int b, const KArgs& a, SmU& sm, int tid) {
  int v0 = 0;
  if (tid < 128) { v0 = (tid < NBK) ? a.cnt_b[tid] : 0; sm.fine.basebuf[tid] = v0; }
  __syncthreads();
  for (int off = 1; off < 128; off <<= 1) {
    int u = 0;
    if (tid < 128 && tid >= off) u = sm.fine.basebuf[tid - off];
    __syncthreads();
    if (tid < 128) sm.fine.basebuf[tid] += u;
    __syncthreads();
  }
  const int wbase = (b == 0) ? 0 : sm.fine.basebuf[b - 1];
  const int cnt = a.cnt_b[b];
  const int nbase = b << 9;
  const int nwin = min(512, NN - nbase);
  const unsigned int* ap = a.arena + (size_t)b * ACAP;

  for (int i = tid; i < 4096; i += 256) sm.fine.bins[i] = 0;
  __syncthreads();
  for (int idx = tid; idx < cnt; idx += 256) {
    const unsigned int p = ap[idx];
    const int key = (int)(((p >> 16) & 511) << 3) | (int)((p & 0xffffu) >> 13);
    atomicAdd(&sm.fine.bins[key], 1);
  }
  __syncthreads();
  const int b16 = tid * 16;
  int sum = 0;
#pragma unroll
  for (int k = 0; k < 16; ++k) sum += sm.fine.bins[b16 + k];
  sm.fine.partials[tid] = sum;
  __syncthreads();
  for (int off = 1; off < 256; off <<= 1) {
    int u = (tid >= off) ? sm.fine.partials[tid - off] : 0;
    __syncthreads();
    sm.fine.partials[tid] += u;
    __syncthreads();
  }
  int run = sm.fine.partials[tid] - sum;
#pragma unroll
  for (int k = 0; k < 16; ++k) {
    const int v = sm.fine.bins[b16 + k];
    sm.fine.bins[b16 + k] = run;
    run += v;
  }
  __syncthreads();
  for (int i = tid; i < nwin; i += 256) a.rs[nbase + i] = wbase + sm.fine.bins[i << 3];
  __syncthreads();
  if (cnt <= FINE_CAP) {
    for (int idx = tid; idx < cnt; idx += 256) {
      const unsigned int p = ap[idx];
      const int key = (int)(((p >> 16) & 511) << 3) | (int)((p & 0xffffu) >> 13);
      const int pos = atomicAdd(&sm.fine.bins[key], 1);
      sm.fine.les[pos] = (unsigned short)(p & 0xffffu);
    }
    __syncthreads();
    for (int i = tid; i < cnt; i += 256) a.es[wbase + i] = sm.fine.les[i];
  } else {
    for (int idx = tid; idx < cnt; idx += 256) {
      const unsigned int p = ap[idx];
      const int key = (int)(((p >> 16) & 511) << 3) | (int)((p & 0xffffu) >> 13);
      const int pos = atomicAdd(&sm.fine.bins[key], 1);
      a.es[wbase + pos] = (unsigned short)(p & 0xffffu);
    }
  }
}

// ---- phase: gather-aggregate one node per wave ----
__device__ void d_gather(int wid, const unsigned short* feat, unsigned short* outp,
                         const int* rs, const unsigned short* es, int lane) {
  const int beg = rs[wid];
  const int end = rs[wid + 1];
  const int off = lane * 2;
  const unsigned int self = *reinterpret_cast<const unsigned int*>(feat + (size_t)wid * DF + off);
  float ax = b2f(self & 0xffff), ay = b2f(self >> 16);
  int j = beg;
  while (j < end && (j & 3)) {
    const unsigned int u = *reinterpret_cast<const unsigned int*>(feat + (size_t)es[j] * DF + off);
    ax += b2f(u & 0xffff); ay += b2f(u >> 16);
    ++j;
  }
  for (; j + 3 < end; j += 4) {
    const uint2 e4 = *reinterpret_cast<const uint2*>(es + j);
    const int s0 = (int)(e4.x & 0xffffu), s1 = (int)(e4.x >> 16);
    const int s2 = (int)(e4.y & 0xffffu), s3 = (int)(e4.y >> 16);
    const unsigned int u0 = *reinterpret_cast<const unsigned int*>(feat + (size_t)s0 * DF + off);
    const unsigned int u1 = *reinterpret_cast<const unsigned int*>(feat + (size_t)s1 * DF + off);
    const unsigned int u2 = *reinterpret_cast<const unsigned int*>(feat + (size_t)s2 * DF + off);
    const unsigned int u3 = *reinterpret_cast<const unsigned int*>(feat + (size_t)s3 * DF + off);
    ax += b2f(u0 & 0xffff) + b2f(u1 & 0xffff) + b2f(u2 & 0xffff) + b2f(u3 & 0xffff);
    ay += b2f(u0 >> 16)    + b2f(u1 >> 16)    + b2f(u2 >> 16)    + b2f(u3 >> 16);
  }
  for (; j < end; ++j) {
    const unsigned int u = *reinterpret_cast<const unsigned int*>(feat + (size_t)es[j] * DF + off);
    ax += b2f(u & 0xffff); ay += b2f(u >> 16);
  }
  const unsigned int o = f2b(ax) | (f2b(ay) << 16);
  *reinterpret_cast<unsigned int*>(outp + (size_t)wid * DF + off) = o;
}

// ---- phase: fused double GEMM over all tiles (Wa staged once per phase) ----
__device__ void d_gemm_phase(const unsigned short* Ab, const unsigned short* Wta,
                             const float* ba, const unsigned short* Wtb, const float* bb,
                             unsigned short* outb, SmU& sm, int bid, int nb, int tid) {
  const int lane = tid & 63;
  const int w = tid >> 6;
  const int col = lane & 15;
  const int kq = lane >> 4;

  for (int i = tid; i < 2048; i += 256)
    *reinterpret_cast<uint4*>(&sm.gemm.WaL[i * 8]) =
        *reinterpret_cast<const uint4*>(&Wta[(size_t)i * 8]);

  float4 bva[8], bvb[8];
#pragma unroll
  for (int nf = 0; nf < 8; ++nf) {
    bva[nf] = *reinterpret_cast<const float4*>(ba + nf * 16 + kq * 4);
    bvb[nf] = *reinterpret_cast<const float4*>(bb + nf * 16 + kq * 4);
  }
  __syncthreads();

  unsigned short* hw = &sm.gemm.hL[w][0];
  for (int t = bid; t < GEMM_TILES; t += nb) {
    const int m = t * 64 + w * 16 + col;
    const int mld = (m < NN) ? m : (NN - 1);
    bf16x8 bc[4];
#pragma unroll
    for (int s = 0; s < 4; ++s)
      bc[s] = *reinterpret_cast<const bf16x8*>(Ab + (size_t)mld * DF + s * 32 + kq * 8);

    f32x4 acc[8];
#pragma unroll
    for (int nf = 0; nf < 8; ++nf) acc[nf] = (f32x4){0.f, 0.f, 0.f, 0.f};
#pragma unroll
    for (int s = 0; s < 4; ++s) {
#pragma unroll
      for (int nf = 0; nf < 8; ++nf) {
        const bf16x8 wa = *reinterpret_cast<const bf16x8*>(
            &sm.gemm.WaL[((s * 4 + kq) * 128 + nf * 16 + col) * 8]);
        acc[nf] = __builtin_amdgcn_mfma_f32_16x16x32_bf16(wa, bc[s], acc[nf], 0, 0, 0);
      }
    }
#pragma unroll
    for (int nf = 0; nf < 8; ++nf) {
      uint2 pk;
      pk.x = f2b(fmaxf(acc[nf][0] + bva[nf].x, 0.f)) | (f2b(fmaxf(acc[nf][1] + bva[nf].y, 0.f)) << 16);
      pk.y = f2b(fmaxf(acc[nf][2] + bva[nf].z, 0.f)) | (f2b(fmaxf(acc[nf][3] + bva[nf].w, 0.f)) << 16);
      *reinterpret_cast<uint2*>(&hw[col * RT + nf * 16 + kq * 4]) = pk;
    }
    asm volatile("s_waitcnt lgkmcnt(0)" ::: "memory");
    __builtin_amdgcn_sched_barrier(0);

    f32x4 acc2[8];
#pragma unroll
    for (int nf = 0; nf < 8; ++nf) acc2[nf] = (f32x4){0.f, 0.f, 0.f, 0.f};
#pragma unroll
    for (int s = 0; s < 4; ++s) {
      const bf16x8 hb = *reinterpret_cast<const bf16x8*>(&hw[col * RT + s * 32 + kq * 8]);
#pragma unroll
      for (int nf = 0; nf < 8; ++nf) {
        const bf16x8 wb = *reinterpret_cast<const bf16x8*>(
            Wtb + ((size_t)(s * 4 + kq) * 128 + nf * 16 + col) * 8);
        acc2[nf] = __builtin_amdgcn_mfma_f32_16x16x32_bf16(wb, hb, acc2[nf], 0, 0, 0);
      }
    }
    if (m < NN) {
#pragma unroll
      for (int nf = 0; nf < 8; ++nf) {
        ushort4 p;
        p.x = (unsigned short)f2b(fmaxf(acc2[nf][0] + bvb[nf].x, 0.f));
        p.y = (unsigned short)f2b(fmaxf(acc2[nf][1] + bvb[nf].y, 0.f));
        p.z = (unsigned short)f2b(fmaxf(acc2[nf][2] + bvb[nf].z, 0.f));
        p.w = (unsigned short)f2b(fmaxf(acc2[nf][3] + bvb[nf].w, 0.f));
        *reinterpret_cast<ushort4*>(outb + (size_t)m * DF + nf * 16 + kq * 4) = p;
      }
    }
  }
}

// ---- phase: segment-mean pooling, one wave per 32-node chunk ----
__device__ void d_pool(int wv, const KArgs& a, int lane) {
  const int n0 = wv * 32;
  const int n1 = min(n0 + 32, NN);
  const int off = lane * 2;
  const int gfirst = a.batch[n0];
  const int glast = a.batch[n1 - 1];
  float ax = 0.f, ay = 0.f;
  if (gfirst == glast) {
#pragma unroll 4
    for (int i = n0; i < n1; ++i) {
      const unsigned int u = *reinterpret_cast<const unsigned int*>(a.H + (size_t)i * DF + off);
      ax += b2f(u & 0xffff); ay += b2f(u >> 16);
    }
    atomAddF(&a.sums[gfirst * DF + off], ax);
    atomAddF(&a.sums[gfirst * DF + off + 1], ay);
    if (lane == 0) atomicAdd(&a.cnts[gfirst], n1 - n0);
  } else {
    int g = gfirst, cnt = 0;
    for (int i = n0; i < n1; ++i) {
      const int gi = a.batch[i];
      if (gi != g) {
        atomAddF(&a.sums[g * DF + off], ax);
        atomAddF(&a.sums[g * DF + off + 1], ay);
        if (lane == 0) atomicAdd(&a.cnts[g], cnt);
        ax = 0.f; ay = 0.f; cnt = 0; g = gi;
      }
      const unsigned int u = *reinterpret_cast<const unsigned int*>(a.H + (size_t)i * DF + off);
      ax += b2f(u & 0xffff); ay += b2f(u >> 16);
      ++cnt;
    }
    atomAddF(&a.sums[g * DF + off], ax);
    atomAddF(&a.sums[g * DF + off + 1], ay);
    if (lane == 0) atomicAdd(&a.cnts[g], cnt);
  }
}

__device__ void d_head(const KArgs& a, int tid) {
  for (int o = tid; o < NG * NC; o += 256) {
    const int g = o / NC, c = o % NC;
    const float inv = 1.f / fmaxf((float)a.cnts[g], 1.f);
    float z = a.bfc[c];
    for (int k = 0; k < DF; ++k)
      z = fmaf(a.sums[g * DF + k] * inv, a.Wfc[k * NC + c], z);
    a.out[o] = 1.f / (1.f + expf(-z));
  }
}

// ======== cooperative mega-kernel ========
__global__ __launch_bounds__(256) void k_mega(KArgs a) {
  __shared__ SmU sm;
  const int tid = threadIdx.x;
  const int bid = blockIdx.x;
  const int nb = gridDim.x;
  cg::grid_group gg = cg::this_grid();
  const int gw = (bid * 256 + tid) >> 6;
  const int nw = nb * 4;

  // phase A: prep (cast + weights) and edge partition
  for (int vb = bid; vb < CAST_GRID + 32; vb += nb) d_prep(vb, a, tid);
  for (int vb = bid; vb < PART_GRID; vb += nb) { d_part(vb, a, sm, tid); __syncthreads(); }
  gg.sync();
  // phase B: fine sort -> rs, es
  if (bid == 0 && tid == 0) a.rs[NN] = NE;
  for (int b = bid; b < NBK; b += nb) { d_fine(b, a, sm, tid); __syncthreads(); }
  gg.sync();
  // conv1
  for (int wid = gw; wid < NN; wid += nw) d_gather(wid, a.xb, a.A, a.rs, a.es, tid & 63);
  gg.sync();
  d_gemm_phase(a.A, a.Wt, a.b1a, a.Wt + DF * DF, a.b1b, a.A, sm, bid, nb, tid);
  gg.sync();
  // conv2
  for (int wid = gw; wid < NN; wid += nw) d_gather(wid, a.A, a.H, a.rs, a.es, tid & 63);
  gg.sync();
  d_gemm_phase(a.H, a.Wt + 2 * DF * DF, a.b2a, a.Wt + 3 * DF * DF, a.b2b, a.H, sm, bid, nb, tid);
  gg.sync();
  // pool + head
  for (int wv = gw; wv < (NN + 31) / 32; wv += nw) d_pool(wv, a, tid & 63);
  gg.sync();
  if (bid == 0) d_head(a, tid);
}

// ======== fallback wrappers (used only if cooperative launch fails) ========
__global__ __launch_bounds__(256) void w_prep(KArgs a) {
  for (int vb = blockIdx.x; vb < CAST_GRID + 32; vb += gridDim.x) d_prep(vb, a, threadIdx.x);
}
__global__ __launch_bounds__(256) void w_part(KArgs a) {
  __shared__ SmU sm;
  for (int vb = blockIdx.x; vb < PART_GRID; vb += gridDim.x) { d_part(vb, a, sm, threadIdx.x); __syncthreads(); }
}
__global__ __launch_bounds__(256) void w_fine(KArgs a) {
  __shared__ SmU sm;
  if (blockIdx.x == 0 && threadIdx.x == 0) a.rs[NN] = NE;
  for (int b = blockIdx.x; b < NBK; b += gridDim.x) { d_fine(b, a, sm, threadIdx.x); __syncthreads(); }
}
__global__ __launch_bounds__(256) void w_gather(const unsigned short* feat, unsigned short* outp,
                                                const int* rs, const unsigned short* es) {
  const int wid = (blockIdx.x * 256 + threadIdx.x) >> 6;
  if (wid < NN) d_gather(wid, feat, outp, rs, es, threadIdx.x & 63);
}
__global__ __launch_bounds__(256) void w_gemm(const unsigned short* Ab, const unsigned short* Wta,
                                              const float* ba, const unsigned short* Wtb,
                                              const float* bb, unsigned short* outb) {
  __shared__ SmU sm;
  d_gemm_phase(Ab, Wta, ba, Wtb, bb, outb, sm, blockIdx.x, gridDim.x, threadIdx.x);
}
__global__ __launch_bounds__(256) void w_pool(KArgs a) {
  const int wv = (blockIdx.x * 256 + threadIdx.x) >> 6;
  if (wv < (NN + 31) / 32) d_pool(wv, a, threadIdx.x & 63);
}
__global__ __launch_bounds__(256) void w_head(KArgs a) {
  if (blockIdx.x == 0) d_head(a, threadIdx.x);
}

extern "C" void kernel_launch(void* const* d_in, const int* in_sizes, int n_in,
                              void* d_out, int out_size, void* d_ws, size_t ws_size,
                              hipStream_t stream)
{
  const float* x   = (const float*)d_in[0];
  const int*   ei  = (const int*)d_in[1];
  const int* batch = (const int*)d_in[2];

  unsigned short* xb = (unsigned short*)d_ws;
  unsigned short* A  = xb + (size_t)NN * DF;
  unsigned short* H  = A + (size_t)NN * DF;
  unsigned short* Wt = H + (size_t)NN * DF;
  float* sums  = (float*)(Wt + (size_t)4 * DF * DF);
  int*   cnts  = (int*)(sums + NG * DF);      // 64
  int*   cnt_b = cnts + 64;                   // 128
  int*   rs    = cnt_b + 128;                 // NN+1, padded to NN+4
  unsigned short* es = (unsigned short*)(rs + (NN + 4));
  unsigned int* arena = (unsigned int*)(es + NE);

  KArgs ka;
  ka.x = x; ka.src = ei; ka.dst = ei + NE; ka.batch = batch;
  ka.W1a = (const float*)d_in[3];  ka.b1a = (const float*)d_in[4];
  ka.W1b = (const float*)d_in[5];  ka.b1b = (const float*)d_in[6];
  ka.W2a = (const float*)d_in[7];  ka.b2a = (const float*)d_in[8];
  ka.W2b = (const float*)d_in[9];  ka.b2b = (const float*)d_in[10];
  ka.Wfc = (const float*)d_in[11]; ka.bfc = (const float*)d_in[12];
  ka.out = (float*)d_out;
  ka.xb = xb; ka.A = A; ka.H = H; ka.Wt = Wt;
  ka.sums = sums; ka.cnts = cnts; ka.cnt_b = cnt_b; ka.rs = rs;
  ka.es = es; ka.arena = arena;

  // zero sums + cnts + cnt_b (contiguous)
  hipMemsetAsync(sums, 0, (size_t)(NG * DF + 64 + 128) * sizeof(float), stream);

  int occ = 0;
  hipError_t oe = hipOccupancyMaxActiveBlocksPerMultiprocessor(&occ, k_mega, 256, 0);
  if (oe != hipSuccess || occ < 1) occ = 1;
  const int grid = occ * 256;   // 256 CUs on MI355X; co-resident by construction

  void* params[] = { (void*)&ka };
  hipError_t rc = hipLaunchCooperativeKernel((void*)k_mega, dim3(grid), dim3(256),
                                             params, 0, stream);
  if (rc != hipSuccess) {
    // fallback: multi-kernel pipeline (identical math)
    w_prep<<<CAST_GRID + 32, 256, 0, stream>>>(ka);
    w_part<<<PART_GRID, 256, 0, stream>>>(ka);
    w_fine<<<NBK, 256, 0, stream>>>(ka);
    w_gather<<<(NN * 64 + 255) / 256, 256, 0, stream>>>(xb, A, rs, es);
    w_gemm<<<GEMM_TILES, 256, 0, stream>>>(A, Wt, ka.b1a, Wt + DF * DF, ka.b1b, A);
    w_gather<<<(NN * 64 + 255) / 256, 256, 0, stream>>>(A, H, rs, es);
    w_gemm<<<GEMM_TILES, 256, 0, stream>>>(H, Wt + 2 * DF * DF, ka.b2a, Wt + 3 * DF * DF, ka.b2b, H);
    w_pool<<<((NN + 31) / 32 + 3) / 4, 256, 0, stream>>>(ka);
    w_head<<<1, 256, 0, stream>>>(ka);
  }
}

// Round 11
// 195.954 us; speedup vs baseline: 3.4414x; 3.4414x over previous
//
#include <hip/hip_runtime.h>

#define NN 50000
#define NE 800000
#define DF 128
#define NG 64
#define NC 10
#define NBK 98            // ceil(NN/512) coarse buckets (dst>>9)
#define PART_CHUNK 4096
#define PART_GRID 196     // 196*4096 >= 800000
#define ACAP 12288        // arena capacity per bucket (avg 8163, max ~8600)
#define FINE_CAP 12288
#define RT 136            // h staging row stride (ushorts)
#define CAST_GRID 6250    // NN*DF/4/256
#define PREP_GRID (CAST_GRID + 32)

typedef short bf16x8 __attribute__((ext_vector_type(8)));
typedef float f32x4  __attribute__((ext_vector_type(4)));

__device__ __forceinline__ void atomAddF(float* p, float v) {
  __hip_atomic_fetch_add(p, v, __ATOMIC_RELAXED, __HIP_MEMORY_SCOPE_AGENT);
}
__device__ __forceinline__ float b2f(unsigned short u) {
  union { unsigned int i; float f; } v; v.i = (unsigned int)u << 16; return v.f;
}
__device__ __forceinline__ unsigned int f2b(float f) {
  unsigned int i = __float_as_uint(f);
  return (i + 0x7fffu + ((i >> 16) & 1u)) >> 16;
}

// ======== merged prep (cast x, weights->fragment-major) + edge partition ========
__global__ __launch_bounds__(256) void k_prep_part(const float* __restrict__ x,
                                                   unsigned short* __restrict__ xb,
                                                   const float* __restrict__ W0,
                                                   const float* __restrict__ W1,
                                                   const float* __restrict__ W2,
                                                   const float* __restrict__ W3,
                                                   unsigned short* __restrict__ Wt,
                                                   const int* __restrict__ src,
                                                   const int* __restrict__ dst,
                                                   int* __restrict__ cnt_b,
                                                   unsigned int* __restrict__ arena)
{
  __shared__ unsigned int stage[PART_CHUNK];
  __shared__ int lhist[128], lcnt[128], lcur[128], gbase[128];
  const int tid = threadIdx.x;
  const int b   = blockIdx.x;

  if (b < CAST_GRID) {
    const int i = b * 256 + tid;
    const float4 v = reinterpret_cast<const float4*>(x)[i];
    uint2 o;
    o.x = f2b(v.x) | (f2b(v.y) << 16);
    o.y = f2b(v.z) | (f2b(v.w) << 16);
    reinterpret_cast<uint2*>(xb)[i] = o;
    return;
  }
  if (b < PREP_GRID) {
    const int o = (b - CAST_GRID) * 256 + tid;
    const int mat = o >> 11;
    const float* W = (mat == 0) ? W0 : (mat == 1) ? W1 : (mat == 2) ? W2 : W3;
    const int rem = o & 2047;
    const int kb = rem >> 7, n = rem & 127;
    unsigned int u[8];
#pragma unroll
    for (int j = 0; j < 8; ++j) u[j] = f2b(W[(size_t)(kb * 8 + j) * DF + n]);
    uint4 p;
    p.x = u[0] | (u[1] << 16);
    p.y = u[2] | (u[3] << 16);
    p.z = u[4] | (u[5] << 16);
    p.w = u[6] | (u[7] << 16);
    *reinterpret_cast<uint4*>(Wt + (size_t)mat * DF * DF + (size_t)rem * 8) = p;
    return;
  }

  // ---- partition block ----
  const int vb = b - PREP_GRID;
  const int e0 = vb * PART_CHUNK;
  const int nE = min(PART_CHUNK, NE - e0);

  for (int i = tid; i < 128; i += 256) lhist[i] = 0;
  __syncthreads();
  unsigned int pk[16]; int bk[16];
#pragma unroll
  for (int i = 0; i < 16; ++i) {
    const int e = e0 + i * 256 + tid;
    if (e < NE) {
      const int d = dst[e], s = src[e];
      const int bb = d >> 9;
      bk[i] = bb;
      pk[i] = ((unsigned int)bb << 25) | ((unsigned int)(d & 511) << 16) | (unsigned int)s;
      atomicAdd(&lhist[bb], 1);
    } else bk[i] = -1;
  }
  __syncthreads();
  for (int i = tid; i < 128; i += 256) lcnt[i] = lhist[i];
  __syncthreads();
  for (int off = 1; off < 128; off <<= 1) {
    int v = 0;
    if (tid < 128 && tid >= off) v = lhist[tid - off];
    __syncthreads();
    if (tid < 128) lhist[tid] += v;
    __syncthreads();
  }
  if (tid < 128) lcur[tid] = lhist[tid] - lcnt[tid];
  __syncthreads();
#pragma unroll
  for (int i = 0; i < 16; ++i)
    if (bk[i] >= 0) {
      const int pos = atomicAdd(&lcur[bk[i]], 1);
      stage[pos] = pk[i];
    }
  __syncthreads();
  if (tid < NBK) {
    const int c = lcnt[tid];
    if (c > 0) gbase[tid] = atomicAdd(&cnt_b[tid], c);
  }
  __syncthreads();
  for (int idx = tid; idx < nE; idx += 256) {
    const unsigned int p = stage[idx];
    const int bb = (int)(p >> 25);
    const int loff = lhist[bb] - lcnt[bb];
    arena[(size_t)bb * ACAP + gbase[bb] + (idx - loff)] = p;
  }
}

// ---- per bucket: self-computed base + counting sort by (dstlocal, src>>13) ----
__global__ __launch_bounds__(256) void k_fine(const unsigned int* __restrict__ arena,
                                              const int* __restrict__ cnt_b,
                                              int* __restrict__ rs,
                                              unsigned short* __restrict__ es)
{
  __shared__ unsigned short les[FINE_CAP];   // 24 KB
  __shared__ int bins[4096];                 // 16 KB
  __shared__ int partials[256];
  __shared__ int basebuf[128];
  const int tid = threadIdx.x;
  const int b   = blockIdx.x;

  if (b == 0 && tid == 0) rs[NN] = NE;

  if (tid < 128) basebuf[tid] = (tid < NBK) ? cnt_b[tid] : 0;
  __syncthreads();
  for (int off = 1; off < 128; off <<= 1) {
    int u = 0;
    if (tid < 128 && tid >= off) u = basebuf[tid - off];
    __syncthreads();
    if (tid < 128) basebuf[tid] += u;
    __syncthreads();
  }
  const int wbase = (b == 0) ? 0 : basebuf[b - 1];
  const int cnt   = cnt_b[b];
  const int nbase = b << 9;
  const int nwin  = min(512, NN - nbase);
  const unsigned int* ap = arena + (size_t)b * ACAP;

  for (int i = tid; i < 4096; i += 256) bins[i] = 0;
  __syncthreads();
  for (int idx = tid; idx < cnt; idx += 256) {
    const unsigned int p = ap[idx];
    const int key = (int)(((p >> 16) & 511) << 3) | (int)((p & 0xffffu) >> 13);
    atomicAdd(&bins[key], 1);
  }
  __syncthreads();
  const int b16 = tid * 16;
  int sum = 0;
#pragma unroll
  for (int k = 0; k < 16; ++k) sum += bins[b16 + k];
  partials[tid] = sum;
  __syncthreads();
  for (int off = 1; off < 256; off <<= 1) {
    int u = (tid >= off) ? partials[tid - off] : 0;
    __syncthreads();
    partials[tid] += u;
    __syncthreads();
  }
  int run = partials[tid] - sum;
#pragma unroll
  for (int k = 0; k < 16; ++k) {
    const int v = bins[b16 + k];
    bins[b16 + k] = run;
    run += v;
  }
  __syncthreads();
  for (int i = tid; i < nwin; i += 256) rs[nbase + i] = wbase + bins[i << 3];
  __syncthreads();
  if (cnt <= FINE_CAP) {
    for (int idx = tid; idx < cnt; idx += 256) {
      const unsigned int p = ap[idx];
      const int key = (int)(((p >> 16) & 511) << 3) | (int)((p & 0xffffu) >> 13);
      const int pos = atomicAdd(&bins[key], 1);
      les[pos] = (unsigned short)(p & 0xffffu);
    }
    __syncthreads();
    for (int i = tid; i < cnt; i += 256) es[wbase + i] = les[i];
  } else {
    for (int idx = tid; idx < cnt; idx += 256) {
      const unsigned int p = ap[idx];
      const int key = (int)(((p >> 16) & 511) << 3) | (int)((p & 0xffffu) >> 13);
      const int pos = atomicAdd(&bins[key], 1);
      es[wbase + pos] = (unsigned short)(p & 0xffffu);
    }
  }
}

// ======== gather-aggregate (bf16): out[i] = feat[i] + sum_j feat[es_j] ========
__global__ __launch_bounds__(256) void k_gather(const unsigned short* __restrict__ feat,
                                                unsigned short* __restrict__ outp,
                                                const int* __restrict__ rs,
                                                const unsigned short* __restrict__ es)
{
  const int wid  = (blockIdx.x * 256 + threadIdx.x) >> 6;
  const int lane = threadIdx.x & 63;
  if (wid >= NN) return;
  const int beg = rs[wid];
  const int end = rs[wid + 1];
  const int off = lane * 2;

  const unsigned int self = *reinterpret_cast<const unsigned int*>(feat + (size_t)wid * DF + off);
  float ax = b2f(self & 0xffff), ay = b2f(self >> 16);
  int j = beg;
  while (j < end && (j & 3)) {
    const unsigned int u = *reinterpret_cast<const unsigned int*>(feat + (size_t)es[j] * DF + off);
    ax += b2f(u & 0xffff); ay += b2f(u >> 16);
    ++j;
  }
  for (; j + 3 < end; j += 4) {
    const uint2 e4 = *reinterpret_cast<const uint2*>(es + j);
    const int s0 = (int)(e4.x & 0xffffu), s1 = (int)(e4.x >> 16);
    const int s2 = (int)(e4.y & 0xffffu), s3 = (int)(e4.y >> 16);
    const unsigned int u0 = *reinterpret_cast<const unsigned int*>(feat + (size_t)s0 * DF + off);
    const unsigned int u1 = *reinterpret_cast<const unsigned int*>(feat + (size_t)s1 * DF + off);
    const unsigned int u2 = *reinterpret_cast<const unsigned int*>(feat + (size_t)s2 * DF + off);
    const unsigned int u3 = *reinterpret_cast<const unsigned int*>(feat + (size_t)s3 * DF + off);
    ax += b2f(u0 & 0xffff) + b2f(u1 & 0xffff) + b2f(u2 & 0xffff) + b2f(u3 & 0xffff);
    ay += b2f(u0 >> 16)    + b2f(u1 >> 16)    + b2f(u2 >> 16)    + b2f(u3 >> 16);
  }
  for (; j < end; ++j) {
    const unsigned int u = *reinterpret_cast<const unsigned int*>(feat + (size_t)es[j] * DF + off);
    ax += b2f(u & 0xffff); ay += b2f(u >> 16);
  }
  const unsigned int o = f2b(ax) | (f2b(ay) << 16);
  *reinterpret_cast<unsigned int*>(outp + (size_t)wid * DF + off) = o;
}

// ======== fused double GEMM: out = relu(relu(A@Wa+ba)@Wb+bb), bf16 MFMA ========
// 256 threads = 4 waves, 16 rows/wave, 64 rows/block, grid 782.
// NO weight staging: Wa/Wb fragments read directly from global (L1/L2-resident,
// shared by all blocks on the CU). LDS = h bounce only (17.4 KB) -> 4 blocks/CU.
__global__ __launch_bounds__(256, 4) void k_gemm2(const unsigned short* __restrict__ Ab,
                                                  const unsigned short* __restrict__ Wta,
                                                  const float* __restrict__ ba,
                                                  const unsigned short* __restrict__ Wtb,
                                                  const float* __restrict__ bb,
                                                  unsigned short* __restrict__ outb, int M)
{
  __shared__ unsigned short hL[4][16 * RT];     // 17.4 KB
  const int tid  = threadIdx.x;
  const int lane = tid & 63;
  const int w    = tid >> 6;
  const int col  = lane & 15;
  const int kq   = lane >> 4;

  const int m   = blockIdx.x * 64 + w * 16 + col;
  const int mld = (m < M) ? m : (M - 1);

  bf16x8 bc[4];
#pragma unroll
  for (int s = 0; s < 4; ++s)
    bc[s] = *reinterpret_cast<const bf16x8*>(Ab + (size_t)mld * DF + s * 32 + kq * 8);

  // ---- GEMM1: Wa fragments from global ----
  f32x4 acc[8];
#pragma unroll
  for (int nf = 0; nf < 8; ++nf) acc[nf] = (f32x4){0.f, 0.f, 0.f, 0.f};
#pragma unroll
  for (int s = 0; s < 4; ++s) {
#pragma unroll
    for (int nf = 0; nf < 8; ++nf) {
      const bf16x8 wa = *reinterpret_cast<const bf16x8*>(
          Wta + ((size_t)(s * 4 + kq) * 128 + nf * 16 + col) * 8);
      acc[nf] = __builtin_amdgcn_mfma_f32_16x16x32_bf16(wa, bc[s], acc[nf], 0, 0, 0);
    }
  }

  // ---- bias_a + relu -> bf16 -> wave-private LDS ----
  unsigned short* hw = &hL[w][0];
#pragma unroll
  for (int nf = 0; nf < 8; ++nf) {
    const float4 bva = *reinterpret_cast<const float4*>(ba + nf * 16 + kq * 4);
    uint2 pk;
    pk.x = f2b(fmaxf(acc[nf][0] + bva.x, 0.f)) | (f2b(fmaxf(acc[nf][1] + bva.y, 0.f)) << 16);
    pk.y = f2b(fmaxf(acc[nf][2] + bva.z, 0.f)) | (f2b(fmaxf(acc[nf][3] + bva.w, 0.f)) << 16);
    *reinterpret_cast<uint2*>(&hw[col * RT + nf * 16 + kq * 4]) = pk;
  }
  asm volatile("s_waitcnt lgkmcnt(0)" ::: "memory");
  __builtin_amdgcn_sched_barrier(0);

  // ---- GEMM2: Wb fragments from global ----
  f32x4 acc2[8];
#pragma unroll
  for (int nf = 0; nf < 8; ++nf) acc2[nf] = (f32x4){0.f, 0.f, 0.f, 0.f};
#pragma unroll
  for (int s = 0; s < 4; ++s) {
    const bf16x8 hb = *reinterpret_cast<const bf16x8*>(&hw[col * RT + s * 32 + kq * 8]);
#pragma unroll
    for (int nf = 0; nf < 8; ++nf) {
      const bf16x8 wb = *reinterpret_cast<const bf16x8*>(
          Wtb + ((size_t)(s * 4 + kq) * 128 + nf * 16 + col) * 8);
      acc2[nf] = __builtin_amdgcn_mfma_f32_16x16x32_bf16(wb, hb, acc2[nf], 0, 0, 0);
    }
  }
  if (m < M) {
#pragma unroll
    for (int nf = 0; nf < 8; ++nf) {
      const float4 bvb = *reinterpret_cast<const float4*>(bb + nf * 16 + kq * 4);
      ushort4 p;
      p.x = (unsigned short)f2b(fmaxf(acc2[nf][0] + bvb.x, 0.f));
      p.y = (unsigned short)f2b(fmaxf(acc2[nf][1] + bvb.y, 0.f));
      p.z = (unsigned short)f2b(fmaxf(acc2[nf][2] + bvb.z, 0.f));
      p.w = (unsigned short)f2b(fmaxf(acc2[nf][3] + bvb.w, 0.f));
      *reinterpret_cast<ushort4*>(outb + (size_t)m * DF + nf * 16 + kq * 4) = p;
    }
  }
}

// ======== segment-mean pooling ========
__global__ __launch_bounds__(256) void k_pool(const unsigned short* __restrict__ h,
                                              const int* __restrict__ batch,
                                              float* __restrict__ sums,
                                              int* __restrict__ cnts)
{
  const int wv   = (blockIdx.x * 256 + threadIdx.x) >> 6;
  const int lane = threadIdx.x & 63;
  const int n0 = wv * 32;
  if (n0 >= NN) return;
  const int n1 = min(n0 + 32, NN);
  const int off = lane * 2;

  const int gfirst = batch[n0];
  const int glast  = batch[n1 - 1];
  float ax = 0.f, ay = 0.f;

  if (gfirst == glast) {
#pragma unroll 4
    for (int i = n0; i < n1; ++i) {
      const unsigned int u = *reinterpret_cast<const unsigned int*>(h + (size_t)i * DF + off);
      ax += b2f(u & 0xffff); ay += b2f(u >> 16);
    }
    atomAddF(&sums[gfirst * DF + off],     ax);
    atomAddF(&sums[gfirst * DF + off + 1], ay);
    if (lane == 0) atomicAdd(&cnts[gfirst], n1 - n0);
  } else {
    int g = gfirst, cnt = 0;
    for (int i = n0; i < n1; ++i) {
      const int gi = batch[i];
      if (gi != g) {
        atomAddF(&sums[g * DF + off],     ax);
        atomAddF(&sums[g * DF + off + 1], ay);
        if (lane == 0) atomicAdd(&cnts[g], cnt);
        ax = 0.f; ay = 0.f; cnt = 0; g = gi;
      }
      const unsigned int u = *reinterpret_cast<const unsigned int*>(h + (size_t)i * DF + off);
      ax += b2f(u & 0xffff); ay += b2f(u >> 16);
      ++cnt;
    }
    atomAddF(&sums[g * DF + off],     ax);
    atomAddF(&sums[g * DF + off + 1], ay);
    if (lane == 0) atomicAdd(&cnts[g], cnt);
  }
}

// ======== head ========
__global__ __launch_bounds__(256) void k_head(const float* __restrict__ sums,
                                              const int* __restrict__ cnts,
                                              const float* __restrict__ Wfc,
                                              const float* __restrict__ bfc,
                                              float* __restrict__ out)
{
  for (int o = threadIdx.x; o < NG * NC; o += 256) {
    const int g = o / NC, c = o % NC;
    const float inv = 1.f / fmaxf((float)cnts[g], 1.f);
    float z = bfc[c];
    for (int k = 0; k < DF; ++k)
      z = fmaf(sums[g * DF + k] * inv, Wfc[k * NC + c], z);
    out[o] = 1.f / (1.f + expf(-z));
  }
}

extern "C" void kernel_launch(void* const* d_in, const int* in_sizes, int n_in,
                              void* d_out, int out_size, void* d_ws, size_t ws_size,
                              hipStream_t stream)
{
  const float* x   = (const float*)d_in[0];
  const int*   ei  = (const int*)d_in[1];
  const int* batch = (const int*)d_in[2];
  const float* W1a = (const float*)d_in[3];
  const float* b1a = (const float*)d_in[4];
  const float* W1b = (const float*)d_in[5];
  const float* b1b = (const float*)d_in[6];
  const float* W2a = (const float*)d_in[7];
  const float* b2a = (const float*)d_in[8];
  const float* W2b = (const float*)d_in[9];
  const float* b2b = (const float*)d_in[10];
  const float* Wfc = (const float*)d_in[11];
  const float* bfc = (const float*)d_in[12];
  float* out = (float*)d_out;

  const int* src = ei;           // edge_index[0]
  const int* dst = ei + NE;      // edge_index[1]

  // ws: [ushort] xb | A | H | Wt(4)  then [int/float] sums | cnts | cnt_b | rs(+pad) | es(u16) | arena
  unsigned short* xb = (unsigned short*)d_ws;
  unsigned short* A  = xb + (size_t)NN * DF;
  unsigned short* H  = A + (size_t)NN * DF;
  unsigned short* Wt = H + (size_t)NN * DF;
  float* sums  = (float*)(Wt + (size_t)4 * DF * DF);
  int*   cnts  = (int*)(sums + NG * DF);      // 64
  int*   cnt_b = cnts + 64;                   // 128
  int*   rs    = cnt_b + 128;                 // NN+1, padded to NN+4
  unsigned short* es = (unsigned short*)(rs + (NN + 4));   // NE u16
  unsigned int* arena = (unsigned int*)(es + NE);          // 98*ACAP u32

  unsigned short* Wt1a = Wt;
  unsigned short* Wt1b = Wt + DF * DF;
  unsigned short* Wt2a = Wt + 2 * DF * DF;
  unsigned short* Wt2b = Wt + 3 * DF * DF;

  const int gemm_grid   = (NN + 63) / 64;            // 782
  const int gather_grid = (NN * 64 + 255) / 256;     // 12500
  const int pool_grid   = ((NN + 31) / 32 + 3) / 4;  // 391

  // ---- prep + CSR build ----
  hipMemsetAsync(sums, 0, (size_t)(NG * DF + 64 + 128) * sizeof(float), stream);
  k_prep_part<<<PREP_GRID + PART_GRID, 256, 0, stream>>>(
      x, xb, W1a, W1b, W2a, W2b, Wt, src, dst, cnt_b, arena);
  k_fine<<<NBK, 256, 0, stream>>>(arena, cnt_b, rs, es);

  // ---- conv1 ----
  k_gather<<<gather_grid, 256, 0, stream>>>(xb, A, rs, es);
  k_gemm2<<<gemm_grid, 256, 0, stream>>>(A, Wt1a, b1a, Wt1b, b1b, A, NN);

  // ---- conv2 ----
  k_gather<<<gather_grid, 256, 0, stream>>>(A, H, rs, es);
  k_gemm2<<<gemm_grid, 256, 0, stream>>>(H, Wt2a, b2a, Wt2b, b2b, H, NN);

  // ---- pool + head ----
  k_pool<<<pool_grid, 256, 0, stream>>>(H, batch, sums, cnts);
  k_head<<<1, 256, 0, stream>>>(sums, cnts, Wfc, bfc, out);
}